// Round 1
// baseline (5621.923 us; speedup 1.0000x reference)
//
#include <hip/hip_runtime.h>
#include <hip/hip_bf16.h>

#define NLAYERS 6
#define BB 8
#define TT 512
#define DMODEL 2048
#define DSTATE 128
#define DCONV 4
#define DINNER 4096
#define NTOK (BB*TT)              // 4096 tokens
#define NCAT (DINNER + 2*DSTATE)  // 4352 = W_dt rows + W_xp rows

typedef __bf16 bf16x8 __attribute__((ext_vector_type(8)));
typedef float floatx4 __attribute__((ext_vector_type(4)));
typedef unsigned short ushort8v __attribute__((ext_vector_type(8)));
typedef unsigned short ushort4v __attribute__((ext_vector_type(4)));

__device__ __forceinline__ float bf2f(unsigned short u) {
    return __uint_as_float(((unsigned)u) << 16);
}
__device__ __forceinline__ unsigned short f2bf(float f) {
    unsigned u = __float_as_uint(f);
    unsigned r = u + 0x7FFFu + ((u >> 16) & 1u);   // round-nearest-even
    return (unsigned short)(r >> 16);
}
__device__ __forceinline__ float siluf(float x) { return x / (1.f + __expf(-x)); }
__device__ __forceinline__ float softplusf(float x) {
    return fmaxf(x, 0.f) + log1pf(__expf(-fabsf(x)));
}

__device__ __forceinline__ void gload16(const void* g, void* l) {
    __builtin_amdgcn_global_load_lds(
        (const __attribute__((address_space(1))) void*)g,
        (__attribute__((address_space(3))) void*)l, 16, 0, 0);
}

// ---------------- fp32 -> bf16 weight conversion ----------------
__global__ __launch_bounds__(256) void cvt_kernel(const float* __restrict__ s,
                                                  unsigned short* __restrict__ d, int n) {
    int i = (blockIdx.x * blockDim.x + threadIdx.x) * 4;
    if (i < n) {
        float4 v = *(const float4*)(s + i);
        ushort4v o = {f2bf(v.x), f2bf(v.y), f2bf(v.z), f2bf(v.w)};
        *(ushort4v*)(d + i) = o;
    }
}

// ---------------- LayerNorm: fp32 in -> bf16 out ----------------
__global__ __launch_bounds__(256) void ln_kernel(const float* __restrict__ x,
                                                 const float* __restrict__ g,
                                                 const float* __restrict__ b,
                                                 unsigned short* __restrict__ out) {
    const int row = blockIdx.x;
    const float* xr = x + (long)row * DMODEL;
    const int base = threadIdx.x * 8;
    float4 v0 = *(const float4*)(xr + base);
    float4 v1 = *(const float4*)(xr + base + 4);
    float vv[8] = {v0.x, v0.y, v0.z, v0.w, v1.x, v1.y, v1.z, v1.w};
    float s = 0.f, s2 = 0.f;
#pragma unroll
    for (int j = 0; j < 8; j++) { s += vv[j]; s2 += vv[j] * vv[j]; }
#pragma unroll
    for (int off = 32; off >= 1; off >>= 1) {
        s += __shfl_xor(s, off);
        s2 += __shfl_xor(s2, off);
    }
    __shared__ float red[8];
    int wave = threadIdx.x >> 6, lane = threadIdx.x & 63;
    if (lane == 0) { red[wave] = s; red[4 + wave] = s2; }
    __syncthreads();
    s = red[0] + red[1] + red[2] + red[3];
    s2 = red[4] + red[5] + red[6] + red[7];
    float mu = s * (1.f / DMODEL);
    float var = s2 * (1.f / DMODEL) - mu * mu;
    float rs = rsqrtf(var + 1e-5f);
    ushort8v ov;
#pragma unroll
    for (int j = 0; j < 8; j++)
        ov[j] = f2bf((vv[j] - mu) * rs * g[base + j] + b[base + j]);
    *(ushort8v*)&out[(long)row * DMODEL + base] = ov;
}

// ---------------- MFMA GEMM: C[M,N] = A[M,K] * B[N,K]^T ----------------
// 128x128 tile, BK=32, 4 waves (2x2), 16x16x32 bf16 MFMA, global_load_lds staging.
// EPI 0: store bf16.  EPI 2: W_dt/W_xp fused (softplus-sum atomics + bc store).
// EPI 3: fp32 store with fp32 residual add.
template <int EPI>
__global__ __launch_bounds__(256) void gemm_bt(const unsigned short* __restrict__ A,
                                               const unsigned short* __restrict__ B,
                                               int K, int ldc,
                                               unsigned short* __restrict__ Cbf,
                                               float* __restrict__ Cf,
                                               const float* __restrict__ resid,
                                               const float* __restrict__ bias,
                                               float* __restrict__ dmean,
                                               float* __restrict__ bcout) {
    __shared__ unsigned short As[128 * 32];
    __shared__ unsigned short Bs[128 * 32];
    const int tid = threadIdx.x;
    const int wave = tid >> 6, lane = tid & 63;
    const int wm = wave >> 1, wn = wave & 1;
    const long rowBase = (long)blockIdx.y * 128;
    const long colBase = (long)blockIdx.x * 128;

    floatx4 acc[4][4];
#pragma unroll
    for (int m = 0; m < 4; m++)
#pragma unroll
        for (int n = 0; n < 4; n++) acc[m][n] = floatx4{0.f, 0.f, 0.f, 0.f};

    const int lrow = lane >> 2;          // 0..15
    const int k0 = (lane & 3) * 8;       // 0,8,16,24
    const unsigned short* Ag = A + (rowBase + wave * 32 + lrow) * (long)K + k0;
    const unsigned short* Bg = B + (colBase + wave * 32 + lrow) * (long)K + k0;
    unsigned short* As0 = &As[wave * 32 * 32];
    unsigned short* Bs0 = &Bs[wave * 32 * 32];

    for (int kt = 0; kt < K; kt += 32) {
        gload16(Ag + kt, As0);
        gload16(Ag + kt + (long)16 * K, As0 + 16 * 32);
        gload16(Bg + kt, Bs0);
        gload16(Bg + kt + (long)16 * K, Bs0 + 16 * 32);
        __syncthreads();   // compiler drains vmcnt before s_barrier

        bf16x8 af[4], bfr[4];
#pragma unroll
        for (int m = 0; m < 4; m++)
            af[m] = *(const bf16x8*)&As[(wm * 64 + m * 16 + (lane & 15)) * 32 + (lane >> 4) * 8];
#pragma unroll
        for (int n = 0; n < 4; n++)
            bfr[n] = *(const bf16x8*)&Bs[(wn * 64 + n * 16 + (lane & 15)) * 32 + (lane >> 4) * 8];
#pragma unroll
        for (int m = 0; m < 4; m++)
#pragma unroll
            for (int n = 0; n < 4; n++)
                acc[m][n] = __builtin_amdgcn_mfma_f32_16x16x32_bf16(af[m], bfr[n], acc[m][n], 0, 0, 0);
        __syncthreads();
    }

    const int r0 = wm * 64 + (lane >> 4) * 4;   // + m*16 + r
    const int c0 = wn * 64 + (lane & 15);       // + n*16

    if (EPI == 0) {
#pragma unroll
        for (int m = 0; m < 4; m++)
#pragma unroll
            for (int n = 0; n < 4; n++)
#pragma unroll
                for (int r = 0; r < 4; r++) {
                    long row = rowBase + r0 + m * 16 + r;
                    long col = colBase + c0 + n * 16;
                    Cbf[row * ldc + col] = f2bf(acc[m][n][r]);
                }
    } else if (EPI == 2) {
        if (colBase >= DINNER) {
            // W_xp region -> bc[NTOK][256]
#pragma unroll
            for (int m = 0; m < 4; m++)
#pragma unroll
                for (int n = 0; n < 4; n++)
#pragma unroll
                    for (int r = 0; r < 4; r++) {
                        long row = rowBase + r0 + m * 16 + r;
                        long col = colBase - DINNER + c0 + n * 16;
                        bcout[row * (2 * DSTATE) + col] = acc[m][n][r];
                    }
        } else {
            // delta region: softplus(acc + b_dt) summed over cols -> dmean atomics
            float bi[4];
#pragma unroll
            for (int n = 0; n < 4; n++) bi[n] = bias[colBase + c0 + n * 16];
#pragma unroll
            for (int m = 0; m < 4; m++)
#pragma unroll
                for (int r = 0; r < 4; r++) {
                    float s = 0.f;
#pragma unroll
                    for (int n = 0; n < 4; n++) s += softplusf(acc[m][n][r] + bi[n]);
                    s += __shfl_xor(s, 1);
                    s += __shfl_xor(s, 2);
                    s += __shfl_xor(s, 4);
                    s += __shfl_xor(s, 8);
                    if ((lane & 15) == 0)
                        atomicAdd(&dmean[rowBase + r0 + m * 16 + r], s);
                }
        }
    } else {  // EPI == 3: fp32 out + residual
#pragma unroll
        for (int m = 0; m < 4; m++)
#pragma unroll
            for (int n = 0; n < 4; n++)
#pragma unroll
                for (int r = 0; r < 4; r++) {
                    long row = rowBase + r0 + m * 16 + r;
                    long col = colBase + c0 + n * 16;
                    Cf[row * ldc + col] = acc[m][n][r] + resid[row * ldc + col];
                }
    }
}

// ---------------- causal depthwise conv1d + bias + silu ----------------
__global__ __launch_bounds__(256) void conv_silu_kernel(const unsigned short* __restrict__ xr,
                                                        const float* __restrict__ w,
                                                        const float* __restrict__ cb,
                                                        unsigned short* __restrict__ xc) {
    int idx = blockIdx.x * blockDim.x + threadIdx.x;   // NTOK * 512
    int d0 = (idx & 511) * 8;
    int bt = idx >> 9;
    int t = bt & (TT - 1);
    float acc[8];
#pragma unroll
    for (int j = 0; j < 8; j++) acc[j] = cb[d0 + j];
#pragma unroll
    for (int k = 0; k < DCONV; k++) {
        int ts = t - (DCONV - 1) + k;
        if (ts < 0) continue;
        ushort8v v = *(const ushort8v*)&xr[(long)(bt - (DCONV - 1) + k) * (2 * DINNER) + d0];
#pragma unroll
        for (int j = 0; j < 8; j++) acc[j] += bf2f(v[j]) * w[(d0 + j) * DCONV + k];
    }
    ushort8v ov;
#pragma unroll
    for (int j = 0; j < 8; j++) ov[j] = f2bf(siluf(acc[j]));
    *(ushort8v*)&xc[(long)bt * DINNER + d0] = ov;
}

// ---------------- sequential selective-scan (1 wave per batch) ----------------
__global__ void scan_kernel(const float* __restrict__ dmean, const float* __restrict__ bcmat,
                            const float* __restrict__ A_log, float* __restrict__ ys) {
    int b = blockIdx.x, lane = threadIdx.x;   // 64 lanes, 2 states each
    float A0 = -expf(A_log[lane]);
    float A1 = -expf(A_log[lane + 64]);
    float h0 = 0.f, h1 = 0.f;
    const float inv = 1.f / (float)DINNER;
    const float* rowp = bcmat + (long)b * TT * (2 * DSTATE);
    const float* dmp = dmean + b * TT;
    float B0 = rowp[lane], B1 = rowp[64 + lane];
    float C0 = rowp[128 + lane], C1 = rowp[192 + lane];
    float DM = dmp[0];
    for (int t = 0; t < TT; t++) {
        float nB0 = 0.f, nB1 = 0.f, nC0 = 0.f, nC1 = 0.f, nDM = 0.f;
        if (t + 1 < TT) {
            const float* nx = rowp + (long)(t + 1) * 256;
            nB0 = nx[lane]; nB1 = nx[64 + lane];
            nC0 = nx[128 + lane]; nC1 = nx[192 + lane];
            nDM = dmp[t + 1];
        }
        float dm = DM * inv;
        h0 = h0 * __expf(dm * A0) + B0;
        h1 = h1 * __expf(dm * A1) + B1;
        float v = h0 * C0 + h1 * C1;
#pragma unroll
        for (int off = 32; off >= 1; off >>= 1) v += __shfl_xor(v, off);
        if (lane == 0) ys[b * TT + t] = v;
        B0 = nB0; B1 = nB1; C0 = nC0; C1 = nC1; DM = nDM;
    }
}

// ---------------- y = (ys + D_skip*xc) * silu(res) ----------------
__global__ __launch_bounds__(256) void ycomb_kernel(const float* __restrict__ ys,
                                                    const unsigned short* __restrict__ xc,
                                                    const unsigned short* __restrict__ xr,
                                                    const float* __restrict__ dskip,
                                                    unsigned short* __restrict__ yc) {
    int idx = blockIdx.x * blockDim.x + threadIdx.x;
    int d0 = (idx & 511) * 8;
    int bt = idx >> 9;
    float y = ys[bt];
    ushort8v xcv = *(const ushort8v*)&xc[(long)bt * DINNER + d0];
    ushort8v rv = *(const ushort8v*)&xr[(long)bt * (2 * DINNER) + DINNER + d0];
    ushort8v ov;
#pragma unroll
    for (int j = 0; j < 8; j++) {
        float val = (y + dskip[d0 + j] * bf2f(xcv[j])) * siluf(bf2f(rv[j]));
        ov[j] = f2bf(val);
    }
    *(ushort8v*)&yc[(long)bt * DINNER + d0] = ov;
}

extern "C" void kernel_launch(void* const* d_in, const int* in_sizes, int n_in,
                              void* d_out, int out_size, void* d_ws, size_t ws_size,
                              hipStream_t stream) {
    const float* x      = (const float*)d_in[0];
    const float* ln_g   = (const float*)d_in[1];
    const float* ln_b   = (const float*)d_in[2];
    const float* W_in   = (const float*)d_in[3];
    const float* conv_w = (const float*)d_in[4];
    const float* conv_b = (const float*)d_in[5];
    const float* W_xp   = (const float*)d_in[6];
    const float* W_dt   = (const float*)d_in[7];
    const float* b_dt   = (const float*)d_in[8];
    const float* A_log  = (const float*)d_in[9];
    const float* D_skip = (const float*)d_in[10];
    const float* W_out  = (const float*)d_in[11];
    float* out = (float*)d_out;

    // workspace carve (all sizes are multiples of 256B)
    char* ws = (char*)d_ws;
    const size_t nWin  = (size_t)2 * DINNER * DMODEL;   // 16,777,216
    const size_t nWdt  = (size_t)DINNER * DINNER;       // 16,777,216
    const size_t nWxp  = (size_t)2 * DSTATE * DINNER;   //  1,048,576
    const size_t nWout = (size_t)DMODEL * DINNER;       //  8,388,608

    unsigned short* wb_in  = (unsigned short*)ws; ws += nWin * 2;
    unsigned short* wb_cat = (unsigned short*)ws; ws += (nWdt + nWxp) * 2;
    unsigned short* wb_out = (unsigned short*)ws; ws += nWout * 2;
    unsigned short* xn = (unsigned short*)ws; ws += (size_t)NTOK * DMODEL * 2;
    unsigned short* xr = (unsigned short*)ws; ws += (size_t)NTOK * 2 * DINNER * 2;
    unsigned short* xc = (unsigned short*)ws; ws += (size_t)NTOK * DINNER * 2;
    unsigned short* yc = (unsigned short*)ws; ws += (size_t)NTOK * DINNER * 2;
    float* bc    = (float*)ws; ws += (size_t)NTOK * 2 * DSTATE * 4;
    float* dmean = (float*)ws; ws += (size_t)NTOK * 4;
    float* ysb   = (float*)ws; ws += (size_t)NTOK * 4;
    float* h0    = (float*)ws; ws += (size_t)NTOK * DMODEL * 4;
    float* h1    = (float*)ws; ws += (size_t)NTOK * DMODEL * 4;

    const float* hin = x;
    for (int l = 0; l < NLAYERS; l++) {
        float* hout = (l == NLAYERS - 1) ? out : ((l & 1) ? h1 : h0);

        // convert this layer's weights to bf16 (W_dt and W_xp concatenated)
        cvt_kernel<<<(int)(nWin / 1024), 256, 0, stream>>>(W_in + (size_t)l * nWin, wb_in, (int)nWin);
        cvt_kernel<<<(int)(nWdt / 1024), 256, 0, stream>>>(W_dt + (size_t)l * nWdt, wb_cat, (int)nWdt);
        cvt_kernel<<<(int)(nWxp / 1024), 256, 0, stream>>>(W_xp + (size_t)l * nWxp, wb_cat + nWdt, (int)nWxp);
        cvt_kernel<<<(int)(nWout / 1024), 256, 0, stream>>>(W_out + (size_t)l * nWout, wb_out, (int)nWout);

        hipMemsetAsync(dmean, 0, (size_t)NTOK * 4, stream);

        // 1) LayerNorm
        ln_kernel<<<NTOK, 256, 0, stream>>>(hin, ln_g + l * DMODEL, ln_b + l * DMODEL, xn);

        // 2) x_and_res = xn @ W_in^T   [4096 x 8192], K=2048
        gemm_bt<0><<<dim3(2 * DINNER / 128, NTOK / 128), 256, 0, stream>>>(
            xn, wb_in, DMODEL, 2 * DINNER, xr, nullptr, nullptr, nullptr, nullptr, nullptr);

        // 3) causal depthwise conv + silu
        conv_silu_kernel<<<NTOK * 512 / 256, 256, 0, stream>>>(
            xr, conv_w + (size_t)l * DINNER * DCONV, conv_b + (size_t)l * DINNER, xc);

        // 4) fused [W_dt; W_xp] GEMM: softplus-mean atomics + bc, K=4096
        gemm_bt<2><<<dim3(NCAT / 128, NTOK / 128), 256, 0, stream>>>(
            xc, wb_cat, DINNER, 0, nullptr, nullptr, nullptr,
            b_dt + (size_t)l * DINNER, dmean, bc);

        // 5) sequential scan -> ys
        scan_kernel<<<BB, 64, 0, stream>>>(dmean, bc, A_log + (size_t)l * DSTATE, ysb);

        // 6) y = (ys + D_skip*xc) * silu(res)
        ycomb_kernel<<<NTOK * 512 / 256, 256, 0, stream>>>(
            ysb, xc, xr, D_skip + (size_t)l * DINNER, yc);

        // 7) out = yc @ W_out^T + hin   [4096 x 2048], K=4096
        gemm_bt<3><<<dim3(DMODEL / 128, NTOK / 128), 256, 0, stream>>>(
            yc, wb_out, DINNER, DMODEL, nullptr, hout, hin, nullptr, nullptr, nullptr);

        hin = hout;
    }
    (void)in_sizes; (void)n_in; (void)out_size; (void)ws_size;
}

// Round 2
// 5216.176 us; speedup vs baseline: 1.0778x; 1.0778x over previous
//
#include <hip/hip_runtime.h>
#include <hip/hip_bf16.h>

#define NLAYERS 6
#define BB 8
#define TT 512
#define DMODEL 2048
#define DSTATE 128
#define DCONV 4
#define DINNER 4096
#define NTOK (BB*TT)              // 4096 tokens
#define NCAT (DINNER + 2*DSTATE)  // 4352 = W_dt rows + W_xp rows

typedef __bf16 bf16x8 __attribute__((ext_vector_type(8)));
typedef float floatx4 __attribute__((ext_vector_type(4)));
typedef unsigned short ushort8v __attribute__((ext_vector_type(8)));
typedef unsigned short ushort4v __attribute__((ext_vector_type(4)));

__device__ __forceinline__ float bf2f(unsigned short u) {
    return __uint_as_float(((unsigned)u) << 16);
}
__device__ __forceinline__ unsigned short f2bf(float f) {
    unsigned u = __float_as_uint(f);
    unsigned r = u + 0x7FFFu + ((u >> 16) & 1u);   // round-nearest-even
    return (unsigned short)(r >> 16);
}
__device__ __forceinline__ float siluf(float x) { return x / (1.f + __expf(-x)); }
__device__ __forceinline__ float softplusf(float x) {
    return fmaxf(x, 0.f) + log1pf(__expf(-fabsf(x)));
}

__device__ __forceinline__ void gload16(const void* g, void* l) {
    __builtin_amdgcn_global_load_lds(
        (const __attribute__((address_space(1))) void*)g,
        (__attribute__((address_space(3))) void*)l, 16, 0, 0);
}

// ---------------- fp32 -> bf16 weight conversion ----------------
__global__ __launch_bounds__(256) void cvt_kernel(const float* __restrict__ s,
                                                  unsigned short* __restrict__ d, int n) {
    int i = (blockIdx.x * blockDim.x + threadIdx.x) * 4;
    if (i < n) {
        float4 v = *(const float4*)(s + i);
        ushort4v o = {f2bf(v.x), f2bf(v.y), f2bf(v.z), f2bf(v.w)};
        *(ushort4v*)(d + i) = o;
    }
}

// ---------------- LayerNorm: fp32 in -> bf16 out ----------------
__global__ __launch_bounds__(256) void ln_kernel(const float* __restrict__ x,
                                                 const float* __restrict__ g,
                                                 const float* __restrict__ b,
                                                 unsigned short* __restrict__ out) {
    const int row = blockIdx.x;
    const float* xr = x + (long)row * DMODEL;
    const int base = threadIdx.x * 8;
    float4 v0 = *(const float4*)(xr + base);
    float4 v1 = *(const float4*)(xr + base + 4);
    float vv[8] = {v0.x, v0.y, v0.z, v0.w, v1.x, v1.y, v1.z, v1.w};
    float s = 0.f, s2 = 0.f;
#pragma unroll
    for (int j = 0; j < 8; j++) { s += vv[j]; s2 += vv[j] * vv[j]; }
#pragma unroll
    for (int off = 32; off >= 1; off >>= 1) {
        s += __shfl_xor(s, off);
        s2 += __shfl_xor(s2, off);
    }
    __shared__ float red[8];
    int wave = threadIdx.x >> 6, lane = threadIdx.x & 63;
    if (lane == 0) { red[wave] = s; red[4 + wave] = s2; }
    __syncthreads();
    s = red[0] + red[1] + red[2] + red[3];
    s2 = red[4] + red[5] + red[6] + red[7];
    float mu = s * (1.f / DMODEL);
    float var = s2 * (1.f / DMODEL) - mu * mu;
    float rs = rsqrtf(var + 1e-5f);
    ushort8v ov;
#pragma unroll
    for (int j = 0; j < 8; j++)
        ov[j] = f2bf((vv[j] - mu) * rs * g[base + j] + b[base + j]);
    *(ushort8v*)&out[(long)row * DMODEL + base] = ov;
}

// ================= 256x256 8-phase MFMA GEMM: C = A[M,K] * B[N,K]^T =================
// 512 thr (8 waves, wm=w>>2, wn=w&3), BK=64, dbuf LDS 128KiB, XOR-swizzled chunks,
// counted vmcnt(2) at phases 4/8 only, setprio around MFMA clusters, XCD swizzle.
// Per-wave output 128x64 (acc[8][4] x floatx4).
// LDS map: A: buf*32768 + half*16384 + row*128 + chunk16;  B: +65536 same.
// Swizzle: chunk c stored at c ^ ((row>>2&1)<<1) ^ ((row>>3&1)<<2)  (row within half).

#define BARR __builtin_amdgcn_s_barrier()
#define LGKM0 do { asm volatile("s_waitcnt lgkmcnt(0)"); __builtin_amdgcn_sched_barrier(0); } while(0)
#define VM2  asm volatile("s_waitcnt vmcnt(2)")
#define PRIO1 __builtin_amdgcn_s_setprio(1)
#define PRIO0 __builtin_amdgcn_s_setprio(0)

#define LDA4(BUF, MH, CK) do { _Pragma("unroll") \
  for (int m_ = 0; m_ < 4; m_++) \
    a_frag[m_] = *(const bf16x8*)(rdA + (BUF)*32768 + ((MH)*64 + m_*16)*128 + (CK)); } while(0)

#define LDB4(BUF, CK) do { _Pragma("unroll") \
  for (int n_ = 0; n_ < 4; n_++) \
    b_frag[n_] = *(const bf16x8*)(rdB + (BUF)*32768 + (n_*16)*128 + (CK)); } while(0)

#define MFMA16(MH) do { _Pragma("unroll") \
  for (int m_ = 0; m_ < 4; m_++) { _Pragma("unroll") \
    for (int n_ = 0; n_ < 4; n_++) \
      acc[(MH)*4+m_][n_] = __builtin_amdgcn_mfma_f32_16x16x32_bf16(a_frag[m_], b_frag[n_], acc[(MH)*4+m_][n_], 0,0,0); } } while(0)

#define STG_A(BUF,H,J,OFF) gload16(sA##H##J + (OFF), ldsw + (BUF)*32768 + (H)*16384 + (J)*8192)
#define STG_B(BUF,H,J,OFF) gload16(sB##H##J + (OFF), ldsw + 65536 + (BUF)*32768 + (H)*16384 + (J)*8192)

template <int EPI>
__global__ __launch_bounds__(512, 2) void gemm256(const unsigned short* __restrict__ A,
                                                  const unsigned short* __restrict__ B,
                                                  int K, int gx, int ldc,
                                                  unsigned short* __restrict__ Cbf,
                                                  float* __restrict__ Cf,
                                                  const float* __restrict__ resid,
                                                  const float* __restrict__ bias,
                                                  float* __restrict__ dmean,
                                                  float* __restrict__ bcout) {
    __shared__ __align__(16) char lds[131072];
    const int tid = threadIdx.x;
    const int w = tid >> 6, lane = tid & 63;
    const int wm = w >> 2, wn = w & 3;
    const int lrow = lane & 15;

    // T1: bijective XCD swizzle (grid always divisible by 8)
    const int nwg = gridDim.x;
    const int per = nwg >> 3;
    const int wg = (blockIdx.x & 7) * per + (blockIdx.x >> 3);
    const int by = wg / gx, bx = wg - by * gx;
    const long rowBase = (long)by * 256;
    const long colBase = (long)bx * 256;

    // LDS read bases (include lane row; chunk byte offsets cb0/cb1 are XOR-swizzled)
    const int swz = (((lane >> 2) & 1) << 1) | (((lane >> 3) & 1) << 2);
    const int cb0 = (((lane >> 4)    ) ^ swz) * 16;
    const int cb1 = (((lane >> 4) | 4) ^ swz) * 16;
    const char* rdA = lds + wm * 16384 + lrow * 128;
    const char* rdB = lds + 65536 + (wn >> 1) * 16384 + (wn & 1) * 8192 + lrow * 128;

    // staging: unit (mat,half,j) = 64 rows x 64 cols; lane covers row j*64+w*8+(lane>>3),
    // source chunk pre-swizzled so linear LDS write lands swizzled (rule 21)
    const int rsub = lane >> 3;
    const int csrc = (lane & 7) ^ (((lane >> 5) & 1) << 1) ^ ((w & 1) << 2);
    char* ldsw = lds + w * 1024;
    const size_t Kb = (size_t)K;
    const char* sA00 = (const char*)(A + (rowBase +   0 +  0 + w*8 + rsub) * Kb) + csrc*16;
    const char* sA01 = (const char*)(A + (rowBase +   0 + 64 + w*8 + rsub) * Kb) + csrc*16;
    const char* sA10 = (const char*)(A + (rowBase + 128 +  0 + w*8 + rsub) * Kb) + csrc*16;
    const char* sA11 = (const char*)(A + (rowBase + 128 + 64 + w*8 + rsub) * Kb) + csrc*16;
    const char* sB00 = (const char*)(B + (colBase +   0 +  0 + w*8 + rsub) * Kb) + csrc*16;
    const char* sB01 = (const char*)(B + (colBase +   0 + 64 + w*8 + rsub) * Kb) + csrc*16;
    const char* sB10 = (const char*)(B + (colBase + 128 +  0 + w*8 + rsub) * Kb) + csrc*16;
    const char* sB11 = (const char*)(B + (colBase + 128 + 64 + w*8 + rsub) * Kb) + csrc*16;

    floatx4 acc[8][4];
#pragma unroll
    for (int m = 0; m < 8; m++)
#pragma unroll
        for (int n = 0; n < 4; n++) acc[m][n] = floatx4{0.f, 0.f, 0.f, 0.f};
    bf16x8 a_frag[4], b_frag[4];

    const int nkt = K >> 6;      // 64-wide K-tiles (even; K = 2048 or 4096)
    const int niter = nkt >> 1;

    // prologue: t0 fully (buf0) + t1.B0 (buf1); leave t1.B0 outstanding
    STG_A(0,0,0,0); STG_A(0,0,1,0); STG_A(0,1,0,0); STG_A(0,1,1,0);
    STG_B(0,0,0,0); STG_B(0,0,1,0); STG_B(0,1,0,0); STG_B(0,1,1,0);
    STG_B(1,0,0,128); STG_B(1,0,1,128);
    VM2;
    BARR;

    for (int i = 0; i < niter; i++) {
        const size_t o1 = (size_t)(2*i + 1) * 128;
        const size_t o2 = (size_t)((2*i + 2 < nkt) ? (2*i + 2) : (nkt - 1)) * 128;
        const size_t o3 = (size_t)((2*i + 3 < nkt) ? (2*i + 3) : (nkt - 1)) * 128;
        // ph1: buf0 (mh0,k0)  | stage t1.B1
        LDA4(0,0,cb0); LDB4(0,cb0);
        STG_B(1,1,0,o1); STG_B(1,1,1,o1);
        BARR; LGKM0; PRIO1; MFMA16(0); PRIO0; BARR;
        // ph2: buf0 (mh1,k0)  | stage t1.A0
        LDA4(0,1,cb0);
        STG_A(1,0,0,o1); STG_A(1,0,1,o1);
        BARR; LGKM0; PRIO1; MFMA16(1); PRIO0; BARR;
        // ph3: buf0 (mh0,k1)  | stage t1.A1
        LDA4(0,0,cb1); LDB4(0,cb1);
        STG_A(1,1,0,o1); STG_A(1,1,1,o1);
        BARR; LGKM0; PRIO1; MFMA16(0); PRIO0; BARR;
        // ph4: buf0 (mh1,k1)  | stage t2.B0 ; counted vmcnt -> t1 fully landed
        LDA4(0,1,cb1);
        STG_B(0,0,0,o2); STG_B(0,0,1,o2);
        VM2;
        BARR; LGKM0; PRIO1; MFMA16(1); PRIO0; BARR;
        // ph5: buf1 (mh0,k0)  | stage t2.B1
        LDA4(1,0,cb0); LDB4(1,cb0);
        STG_B(0,1,0,o2); STG_B(0,1,1,o2);
        BARR; LGKM0; PRIO1; MFMA16(0); PRIO0; BARR;
        // ph6: buf1 (mh1,k0)  | stage t2.A0
        LDA4(1,1,cb0);
        STG_A(0,0,0,o2); STG_A(0,0,1,o2);
        BARR; LGKM0; PRIO1; MFMA16(1); PRIO0; BARR;
        // ph7: buf1 (mh0,k1)  | stage t2.A1
        LDA4(1,0,cb1); LDB4(1,cb1);
        STG_A(0,1,0,o2); STG_A(0,1,1,o2);
        BARR; LGKM0; PRIO1; MFMA16(0); PRIO0; BARR;
        // ph8: buf1 (mh1,k1)  | stage t3.B0 ; counted vmcnt -> t2 fully landed
        LDA4(1,1,cb1);
        STG_B(1,0,0,o3); STG_B(1,0,1,o3);
        VM2;
        BARR; LGKM0; PRIO1; MFMA16(1); PRIO0; BARR;
    }

    // ---------------- epilogue ----------------
    const int r0 = (lane >> 4) * 4;     // C/D: col = lane&15, row = (lane>>4)*4 + reg
    if (EPI == 0) {
#pragma unroll
        for (int mi = 0; mi < 8; mi++)
#pragma unroll
            for (int n = 0; n < 4; n++)
#pragma unroll
                for (int r = 0; r < 4; r++) {
                    long row = rowBase + wm * 128 + mi * 16 + r0 + r;
                    long col = colBase + wn * 64 + n * 16 + lrow;
                    Cbf[row * ldc + col] = f2bf(acc[mi][n][r]);
                }
    } else if (EPI == 2) {
        if (colBase >= DINNER) {
            // W_xp region -> bc[NTOK][256]
#pragma unroll
            for (int mi = 0; mi < 8; mi++)
#pragma unroll
                for (int n = 0; n < 4; n++)
#pragma unroll
                    for (int r = 0; r < 4; r++) {
                        long row = rowBase + wm * 128 + mi * 16 + r0 + r;
                        long col = colBase - DINNER + wn * 64 + n * 16 + lrow;
                        bcout[row * (2 * DSTATE) + col] = acc[mi][n][r];
                    }
        } else {
            // delta region: softplus(acc + b_dt) summed over this block's 64 cols/wave
            float bi[4];
#pragma unroll
            for (int n = 0; n < 4; n++) bi[n] = bias[colBase + wn * 64 + n * 16 + lrow];
#pragma unroll
            for (int mi = 0; mi < 8; mi++)
#pragma unroll
                for (int r = 0; r < 4; r++) {
                    float s = 0.f;
#pragma unroll
                    for (int n = 0; n < 4; n++) s += softplusf(acc[mi][n][r] + bi[n]);
                    s += __shfl_xor(s, 1);
                    s += __shfl_xor(s, 2);
                    s += __shfl_xor(s, 4);
                    s += __shfl_xor(s, 8);
                    if (lrow == 0)
                        atomicAdd(&dmean[rowBase + wm * 128 + mi * 16 + r0 + r], s);
                }
        }
    } else {  // EPI == 3: fp32 out + residual
#pragma unroll
        for (int mi = 0; mi < 8; mi++)
#pragma unroll
            for (int n = 0; n < 4; n++)
#pragma unroll
                for (int r = 0; r < 4; r++) {
                    long row = rowBase + wm * 128 + mi * 16 + r0 + r;
                    long col = colBase + wn * 64 + n * 16 + lrow;
                    Cf[row * ldc + col] = acc[mi][n][r] + resid[row * ldc + col];
                }
    }
}

// ---------------- causal depthwise conv1d + bias + silu ----------------
__global__ __launch_bounds__(256) void conv_silu_kernel(const unsigned short* __restrict__ xr,
                                                        const float* __restrict__ w,
                                                        const float* __restrict__ cb,
                                                        unsigned short* __restrict__ xc) {
    int idx = blockIdx.x * blockDim.x + threadIdx.x;   // NTOK * 512
    int d0 = (idx & 511) * 8;
    int bt = idx >> 9;
    int t = bt & (TT - 1);
    float acc[8];
#pragma unroll
    for (int j = 0; j < 8; j++) acc[j] = cb[d0 + j];
#pragma unroll
    for (int k = 0; k < DCONV; k++) {
        int ts = t - (DCONV - 1) + k;
        if (ts < 0) continue;
        ushort8v v = *(const ushort8v*)&xr[(long)(bt - (DCONV - 1) + k) * (2 * DINNER) + d0];
#pragma unroll
        for (int j = 0; j < 8; j++) acc[j] += bf2f(v[j]) * w[(d0 + j) * DCONV + k];
    }
    ushort8v ov;
#pragma unroll
    for (int j = 0; j < 8; j++) ov[j] = f2bf(siluf(acc[j]));
    *(ushort8v*)&xc[(long)bt * DINNER + d0] = ov;
}

// ---------------- sequential selective-scan (1 wave per batch) ----------------
__global__ void scan_kernel(const float* __restrict__ dmean, const float* __restrict__ bcmat,
                            const float* __restrict__ A_log, float* __restrict__ ys) {
    int b = blockIdx.x, lane = threadIdx.x;   // 64 lanes, 2 states each
    float A0 = -expf(A_log[lane]);
    float A1 = -expf(A_log[lane + 64]);
    float h0 = 0.f, h1 = 0.f;
    const float inv = 1.f / (float)DINNER;
    const float* rowp = bcmat + (long)b * TT * (2 * DSTATE);
    const float* dmp = dmean + b * TT;
    float B0 = rowp[lane], B1 = rowp[64 + lane];
    float C0 = rowp[128 + lane], C1 = rowp[192 + lane];
    float DM = dmp[0];
    for (int t = 0; t < TT; t++) {
        float nB0 = 0.f, nB1 = 0.f, nC0 = 0.f, nC1 = 0.f, nDM = 0.f;
        if (t + 1 < TT) {
            const float* nx = rowp + (long)(t + 1) * 256;
            nB0 = nx[lane]; nB1 = nx[64 + lane];
            nC0 = nx[128 + lane]; nC1 = nx[192 + lane];
            nDM = dmp[t + 1];
        }
        float dm = DM * inv;
        h0 = h0 * __expf(dm * A0) + B0;
        h1 = h1 * __expf(dm * A1) + B1;
        float v = h0 * C0 + h1 * C1;
#pragma unroll
        for (int off = 32; off >= 1; off >>= 1) v += __shfl_xor(v, off);
        if (lane == 0) ys[b * TT + t] = v;
        B0 = nB0; B1 = nB1; C0 = nC0; C1 = nC1; DM = nDM;
    }
}

// ---------------- y = (ys + D_skip*xc) * silu(res) ----------------
__global__ __launch_bounds__(256) void ycomb_kernel(const float* __restrict__ ys,
                                                    const unsigned short* __restrict__ xc,
                                                    const unsigned short* __restrict__ xr,
                                                    const float* __restrict__ dskip,
                                                    unsigned short* __restrict__ yc) {
    int idx = blockIdx.x * blockDim.x + threadIdx.x;
    int d0 = (idx & 511) * 8;
    int bt = idx >> 9;
    float y = ys[bt];
    ushort8v xcv = *(const ushort8v*)&xc[(long)bt * DINNER + d0];
    ushort8v rv = *(const ushort8v*)&xr[(long)bt * (2 * DINNER) + DINNER + d0];
    ushort8v ov;
#pragma unroll
    for (int j = 0; j < 8; j++) {
        float val = (y + dskip[d0 + j] * bf2f(xcv[j])) * siluf(bf2f(rv[j]));
        ov[j] = f2bf(val);
    }
    *(ushort8v*)&yc[(long)bt * DINNER + d0] = ov;
}

extern "C" void kernel_launch(void* const* d_in, const int* in_sizes, int n_in,
                              void* d_out, int out_size, void* d_ws, size_t ws_size,
                              hipStream_t stream) {
    const float* x      = (const float*)d_in[0];
    const float* ln_g   = (const float*)d_in[1];
    const float* ln_b   = (const float*)d_in[2];
    const float* W_in   = (const float*)d_in[3];
    const float* conv_w = (const float*)d_in[4];
    const float* conv_b = (const float*)d_in[5];
    const float* W_xp   = (const float*)d_in[6];
    const float* W_dt   = (const float*)d_in[7];
    const float* b_dt   = (const float*)d_in[8];
    const float* A_log  = (const float*)d_in[9];
    const float* D_skip = (const float*)d_in[10];
    const float* W_out  = (const float*)d_in[11];
    float* out = (float*)d_out;

    // workspace carve
    char* ws = (char*)d_ws;
    const size_t nWin  = (size_t)2 * DINNER * DMODEL;
    const size_t nWdt  = (size_t)DINNER * DINNER;
    const size_t nWxp  = (size_t)2 * DSTATE * DINNER;
    const size_t nWout = (size_t)DMODEL * DINNER;

    unsigned short* wb_in  = (unsigned short*)ws; ws += nWin * 2;
    unsigned short* wb_cat = (unsigned short*)ws; ws += (nWdt + nWxp) * 2;
    unsigned short* wb_out = (unsigned short*)ws; ws += nWout * 2;
    unsigned short* xn = (unsigned short*)ws; ws += (size_t)NTOK * DMODEL * 2;
    unsigned short* xr = (unsigned short*)ws; ws += (size_t)NTOK * 2 * DINNER * 2;
    unsigned short* xc = (unsigned short*)ws; ws += (size_t)NTOK * DINNER * 2;
    unsigned short* yc = (unsigned short*)ws; ws += (size_t)NTOK * DINNER * 2;
    float* bc    = (float*)ws; ws += (size_t)NTOK * 2 * DSTATE * 4;
    float* dmean = (float*)ws; ws += (size_t)NTOK * 4;
    float* ysb   = (float*)ws; ws += (size_t)NTOK * 4;
    float* h0    = (float*)ws; ws += (size_t)NTOK * DMODEL * 4;
    float* h1    = (float*)ws; ws += (size_t)NTOK * DMODEL * 4;

    const float* hin = x;
    for (int l = 0; l < NLAYERS; l++) {
        float* hout = (l == NLAYERS - 1) ? out : ((l & 1) ? h1 : h0);

        cvt_kernel<<<(int)(nWin / 1024), 256, 0, stream>>>(W_in + (size_t)l * nWin, wb_in, (int)nWin);
        cvt_kernel<<<(int)(nWdt / 1024), 256, 0, stream>>>(W_dt + (size_t)l * nWdt, wb_cat, (int)nWdt);
        cvt_kernel<<<(int)(nWxp / 1024), 256, 0, stream>>>(W_xp + (size_t)l * nWxp, wb_cat + nWdt, (int)nWxp);
        cvt_kernel<<<(int)(nWout / 1024), 256, 0, stream>>>(W_out + (size_t)l * nWout, wb_out, (int)nWout);

        hipMemsetAsync(dmean, 0, (size_t)NTOK * 4, stream);

        // 1) LayerNorm
        ln_kernel<<<NTOK, 256, 0, stream>>>(hin, ln_g + l * DMODEL, ln_b + l * DMODEL, xn);

        // 2) x_and_res = xn @ W_in^T   [4096 x 8192], K=2048, grid 512 (16x32)
        gemm256<0><<<16 * 32, 512, 0, stream>>>(
            xn, wb_in, DMODEL, 32, 2 * DINNER, xr, nullptr, nullptr, nullptr, nullptr, nullptr);

        // 3) causal depthwise conv + silu
        conv_silu_kernel<<<NTOK * 512 / 256, 256, 0, stream>>>(
            xr, conv_w + (size_t)l * DINNER * DCONV, conv_b + (size_t)l * DINNER, xc);

        // 4) fused [W_dt; W_xp] GEMM: [4096 x 4352], K=4096, grid 272 (16x17)
        gemm256<2><<<16 * 17, 512, 0, stream>>>(
            xc, wb_cat, DINNER, 17, 0, nullptr, nullptr, nullptr,
            b_dt + (size_t)l * DINNER, dmean, bc);

        // 5) sequential scan -> ys
        scan_kernel<<<BB, 64, 0, stream>>>(dmean, bc, A_log + (size_t)l * DSTATE, ysb);

        // 6) y = (ys + D_skip*xc) * silu(res)
        ycomb_kernel<<<NTOK * 512 / 256, 256, 0, stream>>>(
            ysb, xc, xr, D_skip + (size_t)l * DINNER, yc);

        // 7) out = yc @ W_out^T + hin   [4096 x 2048], K=4096, grid 128 (16x8)
        gemm256<3><<<16 * 8, 512, 0, stream>>>(
            yc, wb_out, DINNER, 8, DMODEL, nullptr, hout, hin, nullptr, nullptr, nullptr);

        hin = hout;
    }
    (void)in_sizes; (void)n_in; (void)out_size; (void)ws_size;
}

// Round 3
// 5183.796 us; speedup vs baseline: 1.0845x; 1.0062x over previous
//
#include <hip/hip_runtime.h>
#include <hip/hip_bf16.h>

#define NLAYERS 6
#define BB 8
#define TT 512
#define DMODEL 2048
#define DSTATE 128
#define DCONV 4
#define DINNER 4096
#define NTOK (BB*TT)              // 4096 tokens
#define NCAT (DINNER + 2*DSTATE)  // 4352 = W_dt rows + W_xp rows

typedef __bf16 bf16x8 __attribute__((ext_vector_type(8)));
typedef float floatx4 __attribute__((ext_vector_type(4)));
typedef unsigned short ushort8v __attribute__((ext_vector_type(8)));
typedef unsigned short ushort4v __attribute__((ext_vector_type(4)));

__device__ __forceinline__ float bf2f(unsigned short u) {
    return __uint_as_float(((unsigned)u) << 16);
}
__device__ __forceinline__ unsigned short f2bf(float f) {
    unsigned u = __float_as_uint(f);
    unsigned r = u + 0x7FFFu + ((u >> 16) & 1u);   // round-nearest-even
    return (unsigned short)(r >> 16);
}
__device__ __forceinline__ float siluf(float x) { return x / (1.f + __expf(-x)); }
__device__ __forceinline__ float softplusf(float x) {
    return fmaxf(x, 0.f) + log1pf(__expf(-fabsf(x)));
}

__device__ __forceinline__ void gload16(const void* g, void* l) {
    __builtin_amdgcn_global_load_lds(
        (const __attribute__((address_space(1))) void*)g,
        (__attribute__((address_space(3))) void*)l, 16, 0, 0);
}

// ---------------- fp32 -> bf16 weight conversion ----------------
__global__ __launch_bounds__(256) void cvt_kernel(const float* __restrict__ s,
                                                  unsigned short* __restrict__ d, int n) {
    int i = (blockIdx.x * blockDim.x + threadIdx.x) * 4;
    if (i < n) {
        float4 v = *(const float4*)(s + i);
        ushort4v o = {f2bf(v.x), f2bf(v.y), f2bf(v.z), f2bf(v.w)};
        *(ushort4v*)(d + i) = o;
    }
}

// ---------------- LayerNorm: fp32 in -> bf16 out ----------------
__global__ __launch_bounds__(256) void ln_kernel(const float* __restrict__ x,
                                                 const float* __restrict__ g,
                                                 const float* __restrict__ b,
                                                 unsigned short* __restrict__ out) {
    const int row = blockIdx.x;
    const float* xr = x + (long)row * DMODEL;
    const int base = threadIdx.x * 8;
    float4 v0 = *(const float4*)(xr + base);
    float4 v1 = *(const float4*)(xr + base + 4);
    float vv[8] = {v0.x, v0.y, v0.z, v0.w, v1.x, v1.y, v1.z, v1.w};
    float s = 0.f, s2 = 0.f;
#pragma unroll
    for (int j = 0; j < 8; j++) { s += vv[j]; s2 += vv[j] * vv[j]; }
#pragma unroll
    for (int off = 32; off >= 1; off >>= 1) {
        s += __shfl_xor(s, off);
        s2 += __shfl_xor(s2, off);
    }
    __shared__ float red[8];
    int wave = threadIdx.x >> 6, lane = threadIdx.x & 63;
    if (lane == 0) { red[wave] = s; red[4 + wave] = s2; }
    __syncthreads();
    s = red[0] + red[1] + red[2] + red[3];
    s2 = red[4] + red[5] + red[6] + red[7];
    float mu = s * (1.f / DMODEL);
    float var = s2 * (1.f / DMODEL) - mu * mu;
    float rs = rsqrtf(var + 1e-5f);
    ushort8v ov;
#pragma unroll
    for (int j = 0; j < 8; j++)
        ov[j] = f2bf((vv[j] - mu) * rs * g[base + j] + b[base + j]);
    *(ushort8v*)&out[(long)row * DMODEL + base] = ov;
}

// ================= 256x256 8-phase MFMA GEMM: C = A[M,K] * B[N,K]^T =================
// 512 thr (8 waves, wm=w>>2, wn=w&3), BK=64, dbuf LDS 128KiB.
// T2 swizzle: stored chunk = logical chunk ^ (row&7)  (full 3 row bits -> conflict-free).
// Staging batched at ph1/ph4/ph5/ph8 so every unit has a uniform 4-phase margin;
// four vmcnt(8) drains, each one full phase before the dependent ds_reads.
// Per-wave output 128x64 (acc[8][4] x floatx4).

#define BARR __builtin_amdgcn_s_barrier()
#define LGKM0 do { asm volatile("s_waitcnt lgkmcnt(0)"); __builtin_amdgcn_sched_barrier(0); } while(0)
#define VM8  asm volatile("s_waitcnt vmcnt(8)")
#define PRIO1 __builtin_amdgcn_s_setprio(1)
#define PRIO0 __builtin_amdgcn_s_setprio(0)

#define LDA4(BUF, MH, CK) do { _Pragma("unroll") \
  for (int m_ = 0; m_ < 4; m_++) \
    a_frag[m_] = *(const bf16x8*)(rdA + (BUF)*32768 + ((MH)*64 + m_*16)*128 + (CK)); } while(0)

#define LDB4(BUF, CK) do { _Pragma("unroll") \
  for (int n_ = 0; n_ < 4; n_++) \
    b_frag[n_] = *(const bf16x8*)(rdB + (BUF)*32768 + (n_*16)*128 + (CK)); } while(0)

#define MFMA16(MH) do { _Pragma("unroll") \
  for (int m_ = 0; m_ < 4; m_++) { _Pragma("unroll") \
    for (int n_ = 0; n_ < 4; n_++) \
      acc[(MH)*4+m_][n_] = __builtin_amdgcn_mfma_f32_16x16x32_bf16(a_frag[m_], b_frag[n_], acc[(MH)*4+m_][n_], 0,0,0); } } while(0)

#define STG_A(BUF,H,J,OFF) gload16(sA##H##J + (OFF), ldsw + (BUF)*32768 + (H)*16384 + (J)*8192)
#define STG_B(BUF,H,J,OFF) gload16(sB##H##J + (OFF), ldsw + 65536 + (BUF)*32768 + (H)*16384 + (J)*8192)

template <int EPI>
__global__ __launch_bounds__(512, 2) void gemm256(const unsigned short* __restrict__ A,
                                                  const unsigned short* __restrict__ B,
                                                  int K, int gx, int ldc,
                                                  unsigned short* __restrict__ Cbf,
                                                  float* __restrict__ Cf,
                                                  const float* __restrict__ resid,
                                                  const float* __restrict__ bias,
                                                  float* __restrict__ dmean,
                                                  float* __restrict__ bcout) {
    __shared__ __align__(16) char lds[131072];
    const int tid = threadIdx.x;
    const int w = tid >> 6, lane = tid & 63;
    const int wm = w >> 2, wn = w & 3;
    const int lrow = lane & 15;

    // T1: bijective XCD swizzle (grid always divisible by 8)
    const int nwg = gridDim.x;
    const int per = nwg >> 3;
    const int wg = (blockIdx.x & 7) * per + (blockIdx.x >> 3);
    const int by = wg / gx, bx = wg - by * gx;
    const long rowBase = (long)by * 256;
    const long colBase = (long)bx * 256;

    // T2 read-side: stored chunk = logical ^ (row&7); row&7 == lane&7 for all frags
    const int cb0 = (((lane >> 4))     ^ (lane & 7)) * 16;
    const int cb1 = (((lane >> 4) | 4) ^ (lane & 7)) * 16;
    const char* rdA = lds + wm * 16384 + lrow * 128;
    const char* rdB = lds + 65536 + (wn >> 1) * 16384 + (wn & 1) * 8192 + lrow * 128;

    // staging: unit (mat,half,j) = 64 rows x 128B; wave w covers rows w*8..w*8+7,
    // lane covers stored slot (lane&7) of row (lane>>3) -> source chunk = slot ^ row
    const int rsub = lane >> 3;
    const int csrc = (lane & 7) ^ (lane >> 3);
    char* ldsw = lds + w * 1024;
    const size_t Kb = (size_t)K;
    const char* sA00 = (const char*)(A + (rowBase +   0 +  0 + w*8 + rsub) * Kb) + csrc*16;
    const char* sA01 = (const char*)(A + (rowBase +   0 + 64 + w*8 + rsub) * Kb) + csrc*16;
    const char* sA10 = (const char*)(A + (rowBase + 128 +  0 + w*8 + rsub) * Kb) + csrc*16;
    const char* sA11 = (const char*)(A + (rowBase + 128 + 64 + w*8 + rsub) * Kb) + csrc*16;
    const char* sB00 = (const char*)(B + (colBase +   0 +  0 + w*8 + rsub) * Kb) + csrc*16;
    const char* sB01 = (const char*)(B + (colBase +   0 + 64 + w*8 + rsub) * Kb) + csrc*16;
    const char* sB10 = (const char*)(B + (colBase + 128 +  0 + w*8 + rsub) * Kb) + csrc*16;
    const char* sB11 = (const char*)(B + (colBase + 128 + 64 + w*8 + rsub) * Kb) + csrc*16;

    floatx4 acc[8][4];
#pragma unroll
    for (int m = 0; m < 8; m++)
#pragma unroll
        for (int n = 0; n < 4; n++) acc[m][n] = floatx4{0.f, 0.f, 0.f, 0.f};
    bf16x8 a_frag[4], b_frag[4];

    const int nkt = K >> 6;      // 64-wide K-tiles (even; K = 2048 or 4096)
    const int niter = nkt >> 1;

    // prologue: a=tile0 (all), b=tile1 (B0,B1,Aj0); leave [a.Aj1, b.B0,B1,Aj0]=8 in flight
    STG_B(0,0,0,0);   STG_B(0,0,1,0);      // a.B0
    STG_B(0,1,0,0);   STG_B(0,1,1,0);      // a.B1
    STG_A(0,0,0,0);   STG_A(0,1,0,0);      // a.Aj0
    STG_A(0,0,1,0);   STG_A(0,1,1,0);      // a.Aj1
    STG_B(1,0,0,128); STG_B(1,0,1,128);    // b.B0
    STG_B(1,1,0,128); STG_B(1,1,1,128);    // b.B1
    STG_A(1,0,0,128); STG_A(1,1,0,128);    // b.Aj0
    VM8;   // drain a.B0,B1,Aj0
    BARR;

    for (int i = 0; i < niter; i++) {
        const size_t ob  = (size_t)(2*i + 1) * 128;
        const size_t oa2 = (size_t)((2*i + 2 < nkt) ? (2*i + 2) : (nkt - 1)) * 128;
        const size_t ob2 = (size_t)((2*i + 3 < nkt) ? (2*i + 3) : (nkt - 1)) * 128;
        // ph1: buf0 mh0 k0 | stage b.Aj1 | drain a.Aj1 (needed ph2)
        LDA4(0,0,cb0); LDB4(0,cb0);
        STG_A(1,0,1,ob); STG_A(1,1,1,ob);
        VM8;
        BARR; LGKM0; PRIO1; MFMA16(0); PRIO0; BARR;
        // ph2: buf0 mh1 k0
        LDA4(0,1,cb0);
        BARR; LGKM0; PRIO1; MFMA16(1); PRIO0; BARR;
        // ph3: buf0 mh0 k1
        LDA4(0,0,cb1); LDB4(0,cb1);
        BARR; LGKM0; PRIO1; MFMA16(0); PRIO0; BARR;
        // ph4: buf0 mh1 k1 | stage a'.B0,B1,Aj0 | drain b.B0,B1,Aj0 (needed ph5)
        LDA4(0,1,cb1);
        STG_B(0,0,0,oa2); STG_B(0,0,1,oa2);
        STG_B(0,1,0,oa2); STG_B(0,1,1,oa2);
        STG_A(0,0,0,oa2); STG_A(0,1,0,oa2);
        VM8;
        BARR; LGKM0; PRIO1; MFMA16(1); PRIO0; BARR;
        // ph5: buf1 mh0 k0 | stage a'.Aj1 | drain b.Aj1 (needed ph6)
        LDA4(1,0,cb0); LDB4(1,cb0);
        STG_A(0,0,1,oa2); STG_A(0,1,1,oa2);
        VM8;
        BARR; LGKM0; PRIO1; MFMA16(0); PRIO0; BARR;
        // ph6: buf1 mh1 k0
        LDA4(1,1,cb0);
        BARR; LGKM0; PRIO1; MFMA16(1); PRIO0; BARR;
        // ph7: buf1 mh0 k1
        LDA4(1,0,cb1); LDB4(1,cb1);
        BARR; LGKM0; PRIO1; MFMA16(0); PRIO0; BARR;
        // ph8: buf1 mh1 k1 | stage b'.B0,B1,Aj0 | drain a'.B0,B1,Aj0 (needed ph1')
        LDA4(1,1,cb1);
        STG_B(1,0,0,ob2); STG_B(1,0,1,ob2);
        STG_B(1,1,0,ob2); STG_B(1,1,1,ob2);
        STG_A(1,0,0,ob2); STG_A(1,1,0,ob2);
        VM8;
        BARR; LGKM0; PRIO1; MFMA16(1); PRIO0; BARR;
    }

    // ---------------- epilogue ----------------
    const int r0 = (lane >> 4) * 4;     // C/D: col = lane&15, row = (lane>>4)*4 + reg
    if (EPI == 0) {
#pragma unroll
        for (int mi = 0; mi < 8; mi++)
#pragma unroll
            for (int n = 0; n < 4; n++)
#pragma unroll
                for (int r = 0; r < 4; r++) {
                    long row = rowBase + wm * 128 + mi * 16 + r0 + r;
                    long col = colBase + wn * 64 + n * 16 + lrow;
                    Cbf[row * ldc + col] = f2bf(acc[mi][n][r]);
                }
    } else if (EPI == 2) {
        if (colBase >= DINNER) {
            // W_xp region -> bc[NTOK][256]
#pragma unroll
            for (int mi = 0; mi < 8; mi++)
#pragma unroll
                for (int n = 0; n < 4; n++)
#pragma unroll
                    for (int r = 0; r < 4; r++) {
                        long row = rowBase + wm * 128 + mi * 16 + r0 + r;
                        long col = colBase - DINNER + wn * 64 + n * 16 + lrow;
                        bcout[row * (2 * DSTATE) + col] = acc[mi][n][r];
                    }
        } else {
            // delta region: softplus(acc + b_dt) summed over this block's 64 cols/wave
            float bi[4];
#pragma unroll
            for (int n = 0; n < 4; n++) bi[n] = bias[colBase + wn * 64 + n * 16 + lrow];
#pragma unroll
            for (int mi = 0; mi < 8; mi++)
#pragma unroll
                for (int r = 0; r < 4; r++) {
                    float s = 0.f;
#pragma unroll
                    for (int n = 0; n < 4; n++) s += softplusf(acc[mi][n][r] + bi[n]);
                    s += __shfl_xor(s, 1);
                    s += __shfl_xor(s, 2);
                    s += __shfl_xor(s, 4);
                    s += __shfl_xor(s, 8);
                    if (lrow == 0)
                        atomicAdd(&dmean[rowBase + wm * 128 + mi * 16 + r0 + r], s);
                }
        }
    } else {  // EPI == 3: fp32 out + residual
#pragma unroll
        for (int mi = 0; mi < 8; mi++)
#pragma unroll
            for (int n = 0; n < 4; n++)
#pragma unroll
                for (int r = 0; r < 4; r++) {
                    long row = rowBase + wm * 128 + mi * 16 + r0 + r;
                    long col = colBase + wn * 64 + n * 16 + lrow;
                    Cf[row * ldc + col] = acc[mi][n][r] + resid[row * ldc + col];
                }
    }
}

// ---------------- causal depthwise conv1d + bias + silu ----------------
__global__ __launch_bounds__(256) void conv_silu_kernel(const unsigned short* __restrict__ xr,
                                                        const float* __restrict__ w,
                                                        const float* __restrict__ cb,
                                                        unsigned short* __restrict__ xc) {
    int idx = blockIdx.x * blockDim.x + threadIdx.x;   // NTOK * 512
    int d0 = (idx & 511) * 8;
    int bt = idx >> 9;
    int t = bt & (TT - 1);
    float acc[8];
#pragma unroll
    for (int j = 0; j < 8; j++) acc[j] = cb[d0 + j];
#pragma unroll
    for (int k = 0; k < DCONV; k++) {
        int ts = t - (DCONV - 1) + k;
        if (ts < 0) continue;
        ushort8v v = *(const ushort8v*)&xr[(long)(bt - (DCONV - 1) + k) * (2 * DINNER) + d0];
#pragma unroll
        for (int j = 0; j < 8; j++) acc[j] += bf2f(v[j]) * w[(d0 + j) * DCONV + k];
    }
    ushort8v ov;
#pragma unroll
    for (int j = 0; j < 8; j++) ov[j] = f2bf(siluf(acc[j]));
    *(ushort8v*)&xc[(long)bt * DINNER + d0] = ov;
}

// ---------------- sequential selective-scan (1 wave per batch) ----------------
__global__ void scan_kernel(const float* __restrict__ dmean, const float* __restrict__ bcmat,
                            const float* __restrict__ A_log, float* __restrict__ ys) {
    int b = blockIdx.x, lane = threadIdx.x;   // 64 lanes, 2 states each
    float A0 = -expf(A_log[lane]);
    float A1 = -expf(A_log[lane + 64]);
    float h0 = 0.f, h1 = 0.f;
    const float inv = 1.f / (float)DINNER;
    const float* rowp = bcmat + (long)b * TT * (2 * DSTATE);
    const float* dmp = dmean + b * TT;
    float B0 = rowp[lane], B1 = rowp[64 + lane];
    float C0 = rowp[128 + lane], C1 = rowp[192 + lane];
    float DM = dmp[0];
    for (int t = 0; t < TT; t++) {
        float nB0 = 0.f, nB1 = 0.f, nC0 = 0.f, nC1 = 0.f, nDM = 0.f;
        if (t + 1 < TT) {
            const float* nx = rowp + (long)(t + 1) * 256;
            nB0 = nx[lane]; nB1 = nx[64 + lane];
            nC0 = nx[128 + lane]; nC1 = nx[192 + lane];
            nDM = dmp[t + 1];
        }
        float dm = DM * inv;
        h0 = h0 * __expf(dm * A0) + B0;
        h1 = h1 * __expf(dm * A1) + B1;
        float v = h0 * C0 + h1 * C1;
#pragma unroll
        for (int off = 32; off >= 1; off >>= 1) v += __shfl_xor(v, off);
        if (lane == 0) ys[b * TT + t] = v;
        B0 = nB0; B1 = nB1; C0 = nC0; C1 = nC1; DM = nDM;
    }
}

// ---------------- y = (ys + D_skip*xc) * silu(res) ----------------
__global__ __launch_bounds__(256) void ycomb_kernel(const float* __restrict__ ys,
                                                    const unsigned short* __restrict__ xc,
                                                    const unsigned short* __restrict__ xr,
                                                    const float* __restrict__ dskip,
                                                    unsigned short* __restrict__ yc) {
    int idx = blockIdx.x * blockDim.x + threadIdx.x;
    int d0 = (idx & 511) * 8;
    int bt = idx >> 9;
    float y = ys[bt];
    ushort8v xcv = *(const ushort8v*)&xc[(long)bt * DINNER + d0];
    ushort8v rv = *(const ushort8v*)&xr[(long)bt * (2 * DINNER) + DINNER + d0];
    ushort8v ov;
#pragma unroll
    for (int j = 0; j < 8; j++) {
        float val = (y + dskip[d0 + j] * bf2f(xcv[j])) * siluf(bf2f(rv[j]));
        ov[j] = f2bf(val);
    }
    *(ushort8v*)&yc[(long)bt * DINNER + d0] = ov;
}

extern "C" void kernel_launch(void* const* d_in, const int* in_sizes, int n_in,
                              void* d_out, int out_size, void* d_ws, size_t ws_size,
                              hipStream_t stream) {
    const float* x      = (const float*)d_in[0];
    const float* ln_g   = (const float*)d_in[1];
    const float* ln_b   = (const float*)d_in[2];
    const float* W_in   = (const float*)d_in[3];
    const float* conv_w = (const float*)d_in[4];
    const float* conv_b = (const float*)d_in[5];
    const float* W_xp   = (const float*)d_in[6];
    const float* W_dt   = (const float*)d_in[7];
    const float* b_dt   = (const float*)d_in[8];
    const float* A_log  = (const float*)d_in[9];
    const float* D_skip = (const float*)d_in[10];
    const float* W_out  = (const float*)d_in[11];
    float* out = (float*)d_out;

    // workspace carve
    char* ws = (char*)d_ws;
    const size_t nWin  = (size_t)2 * DINNER * DMODEL;
    const size_t nWdt  = (size_t)DINNER * DINNER;
    const size_t nWxp  = (size_t)2 * DSTATE * DINNER;
    const size_t nWout = (size_t)DMODEL * DINNER;

    unsigned short* wb_in  = (unsigned short*)ws; ws += nWin * 2;
    unsigned short* wb_cat = (unsigned short*)ws; ws += (nWdt + nWxp) * 2;
    unsigned short* wb_out = (unsigned short*)ws; ws += nWout * 2;
    unsigned short* xn = (unsigned short*)ws; ws += (size_t)NTOK * DMODEL * 2;
    unsigned short* xr = (unsigned short*)ws; ws += (size_t)NTOK * 2 * DINNER * 2;
    unsigned short* xc = (unsigned short*)ws; ws += (size_t)NTOK * DINNER * 2;
    unsigned short* yc = (unsigned short*)ws; ws += (size_t)NTOK * DINNER * 2;
    float* bc    = (float*)ws; ws += (size_t)NTOK * 2 * DSTATE * 4;
    float* dmean = (float*)ws; ws += (size_t)NTOK * 4;
    float* ysb   = (float*)ws; ws += (size_t)NTOK * 4;
    float* h0    = (float*)ws; ws += (size_t)NTOK * DMODEL * 4;
    float* h1    = (float*)ws; ws += (size_t)NTOK * DMODEL * 4;

    const float* hin = x;
    for (int l = 0; l < NLAYERS; l++) {
        float* hout = (l == NLAYERS - 1) ? out : ((l & 1) ? h1 : h0);

        cvt_kernel<<<(int)(nWin / 1024), 256, 0, stream>>>(W_in + (size_t)l * nWin, wb_in, (int)nWin);
        cvt_kernel<<<(int)(nWdt / 1024), 256, 0, stream>>>(W_dt + (size_t)l * nWdt, wb_cat, (int)nWdt);
        cvt_kernel<<<(int)(nWxp / 1024), 256, 0, stream>>>(W_xp + (size_t)l * nWxp, wb_cat + nWdt, (int)nWxp);
        cvt_kernel<<<(int)(nWout / 1024), 256, 0, stream>>>(W_out + (size_t)l * nWout, wb_out, (int)nWout);

        hipMemsetAsync(dmean, 0, (size_t)NTOK * 4, stream);

        // 1) LayerNorm
        ln_kernel<<<NTOK, 256, 0, stream>>>(hin, ln_g + l * DMODEL, ln_b + l * DMODEL, xn);

        // 2) x_and_res = xn @ W_in^T   [4096 x 8192], K=2048, grid 512 (16x32)
        gemm256<0><<<16 * 32, 512, 0, stream>>>(
            xn, wb_in, DMODEL, 32, 2 * DINNER, xr, nullptr, nullptr, nullptr, nullptr, nullptr);

        // 3) causal depthwise conv + silu
        conv_silu_kernel<<<NTOK * 512 / 256, 256, 0, stream>>>(
            xr, conv_w + (size_t)l * DINNER * DCONV, conv_b + (size_t)l * DINNER, xc);

        // 4) fused [W_dt; W_xp] GEMM: [4096 x 4352], K=4096, grid 272 (16x17)
        gemm256<2><<<16 * 17, 512, 0, stream>>>(
            xc, wb_cat, DINNER, 17, 0, nullptr, nullptr, nullptr,
            b_dt + (size_t)l * DINNER, dmean, bc);

        // 5) sequential scan -> ys
        scan_kernel<<<BB, 64, 0, stream>>>(dmean, bc, A_log + (size_t)l * DSTATE, ysb);

        // 6) y = (ys + D_skip*xc) * silu(res)
        ycomb_kernel<<<NTOK * 512 / 256, 256, 0, stream>>>(
            ysb, xc, xr, D_skip + (size_t)l * DINNER, yc);

        // 7) out = yc @ W_out^T + hin   [4096 x 2048], K=4096, grid 128 (16x8)
        gemm256<3><<<16 * 8, 512, 0, stream>>>(
            yc, wb_out, DINNER, 8, DMODEL, nullptr, hout, hin, nullptr, nullptr, nullptr);

        hin = hout;
    }
    (void)in_sizes; (void)n_in; (void)out_size; (void)ws_size;
}

// Round 4
// 4894.877 us; speedup vs baseline: 1.1485x; 1.0590x over previous
//
#include <hip/hip_runtime.h>
#include <hip/hip_bf16.h>

#define NLAYERS 6
#define BB 8
#define TT 512
#define DMODEL 2048
#define DSTATE 128
#define DCONV 4
#define DINNER 4096
#define NTOK (BB*TT)              // 4096 tokens
#define NCAT (DINNER + 2*DSTATE)  // 4352 = W_dt rows + W_xp rows

typedef __bf16 bf16x8 __attribute__((ext_vector_type(8)));
typedef float floatx4 __attribute__((ext_vector_type(4)));
typedef unsigned short ushort8v __attribute__((ext_vector_type(8)));
typedef unsigned short ushort4v __attribute__((ext_vector_type(4)));

__device__ __forceinline__ float bf2f(unsigned short u) {
    return __uint_as_float(((unsigned)u) << 16);
}
__device__ __forceinline__ unsigned short f2bf(float f) {
    unsigned u = __float_as_uint(f);
    unsigned r = u + 0x7FFFu + ((u >> 16) & 1u);   // round-nearest-even
    return (unsigned short)(r >> 16);
}
__device__ __forceinline__ float siluf(float x) { return x / (1.f + __expf(-x)); }
__device__ __forceinline__ float softplusf(float x) {
    return fmaxf(x, 0.f) + log1pf(__expf(-fabsf(x)));
}

__device__ __forceinline__ void gload16(const void* g, void* l) {
    __builtin_amdgcn_global_load_lds(
        (const __attribute__((address_space(1))) void*)g,
        (__attribute__((address_space(3))) void*)l, 16, 0, 0);
}

// ---------------- fp32 -> bf16 weight conversion ----------------
__global__ __launch_bounds__(256) void cvt_kernel(const float* __restrict__ s,
                                                  unsigned short* __restrict__ d, int n) {
    int i = (blockIdx.x * blockDim.x + threadIdx.x) * 4;
    if (i < n) {
        float4 v = *(const float4*)(s + i);
        ushort4v o = {f2bf(v.x), f2bf(v.y), f2bf(v.z), f2bf(v.w)};
        *(ushort4v*)(d + i) = o;
    }
}

// ---------------- LayerNorm: fp32 in -> bf16 out ----------------
__global__ __launch_bounds__(256) void ln_kernel(const float* __restrict__ x,
                                                 const float* __restrict__ g,
                                                 const float* __restrict__ b,
                                                 unsigned short* __restrict__ out) {
    const int row = blockIdx.x;
    const float* xr = x + (long)row * DMODEL;
    const int base = threadIdx.x * 8;
    float4 v0 = *(const float4*)(xr + base);
    float4 v1 = *(const float4*)(xr + base + 4);
    float vv[8] = {v0.x, v0.y, v0.z, v0.w, v1.x, v1.y, v1.z, v1.w};
    float s = 0.f, s2 = 0.f;
#pragma unroll
    for (int j = 0; j < 8; j++) { s += vv[j]; s2 += vv[j] * vv[j]; }
#pragma unroll
    for (int off = 32; off >= 1; off >>= 1) {
        s += __shfl_xor(s, off);
        s2 += __shfl_xor(s2, off);
    }
    __shared__ float red[8];
    int wave = threadIdx.x >> 6, lane = threadIdx.x & 63;
    if (lane == 0) { red[wave] = s; red[4 + wave] = s2; }
    __syncthreads();
    s = red[0] + red[1] + red[2] + red[3];
    s2 = red[4] + red[5] + red[6] + red[7];
    float mu = s * (1.f / DMODEL);
    float var = s2 * (1.f / DMODEL) - mu * mu;
    float rs = rsqrtf(var + 1e-5f);
    ushort8v ov;
#pragma unroll
    for (int j = 0; j < 8; j++)
        ov[j] = f2bf((vv[j] - mu) * rs * g[base + j] + b[base + j]);
    *(ushort8v*)&out[(long)row * DMODEL + base] = ov;
}

// ============ (64*MH)x256 MFMA GEMM, 2 barriers per K-tile: C = A[M,K]*B[N,K]^T ============
// 512 thr (8 waves: wm=w>>2 M-split, wn=w&3 N-split), BK=64, double-buffered LDS.
// LDS: A rows linear row*128B (MH*8KB/buf, 2 bufs), then B (32KB/buf, 2 bufs).
// T2 swizzle: stored 16B chunk = logical ^ (row&7) on both write-source and read (verified: 0 conflicts).
// Schedule per K-tile t (buf=t&1):
//   LD(k0) ; lgkm0 ; MFMA(k0)            <- outside barriers: wave-skew overlaps reads/MFMA
//   LD(k1) ; lgkm0 ; BARR                <- all reads from buf done
//   STAGE(t+2 -> buf) ; vmcnt(MH+4) ; BARR   <- t+1 landed everywhere, t+2 left in flight
//   MFMA(k1)                             <- register-only, overlaps t+2 staging
// Epilogue: swapped-operand MFMA => lane holds 4 consecutive N-cols -> 8B/16B stores.

#define BARR __builtin_amdgcn_s_barrier()
#define LGKM0 do { asm volatile("s_waitcnt lgkmcnt(0)"); __builtin_amdgcn_sched_barrier(0); } while(0)
#define PRIO1 __builtin_amdgcn_s_setprio(1)
#define PRIO0 __builtin_amdgcn_s_setprio(0)

template <int EPI, int MH>
__global__ __launch_bounds__(512, 2) void gemm256(const unsigned short* __restrict__ A,
                                                  const unsigned short* __restrict__ B,
                                                  int K, int gx, int ldc,
                                                  unsigned short* __restrict__ Cbf,
                                                  float* __restrict__ Cf,
                                                  const float* __restrict__ resid,
                                                  const float* __restrict__ bias,
                                                  float* __restrict__ dmean,
                                                  float* __restrict__ bcout) {
    constexpr int MI = MH * 2;          // A-frags (16-row bands) per wave per k-half
    constexpr int WBAND = MH * 32;      // wave M-band stride in rows
    __shared__ __align__(16) char lds[MH * 16384 + 65536];
    const int tid = threadIdx.x;
    const int w = tid >> 6, lane = tid & 63;
    const int wm = w >> 2, wn = w & 3;
    const int lrow = lane & 15;

    // T1: bijective XCD swizzle (all grids divisible by 8)
    const int nwg = gridDim.x;
    const int per = nwg >> 3;
    const int wg = (blockIdx.x & 7) * per + (blockIdx.x >> 3);
    const int by = wg / gx, bx = wg - by * gx;
    const long rowBase = (long)by * (MH * 64);
    const long colBase = (long)bx * 256;

    // T2 read-side: stored chunk = logical ^ (row&7); row&7 == lane&7 for all frags
    const int cb0 = (((lane >> 4))     ^ (lane & 7)) * 16;
    const int cb1 = (((lane >> 4) | 4) ^ (lane & 7)) * 16;
    const char* rdA = lds + wm * (MH / 2) * 8192 + lrow * 128;
    const char* rdB = lds + MH * 16384 + wn * 8192 + lrow * 128;

    // staging: unit = 64 rows x 128B; wave w covers rows w*8..w*8+7 of each unit;
    // lane writes stored slot (lane&7) of row (lane>>3) -> source chunk = slot ^ row
    const int rsub = lane >> 3;
    const int csrc = (lane & 7) ^ (lane >> 3);
    char* ldsw = lds + w * 1024;
    const size_t Kb = (size_t)K;
    const char* pA[MH];
#pragma unroll
    for (int u = 0; u < MH; u++)
        pA[u] = (const char*)(A + (rowBase + u * 64 + w * 8 + rsub) * Kb) + csrc * 16;
    const char* pB[4];
#pragma unroll
    for (int u = 0; u < 4; u++)
        pB[u] = (const char*)(B + (colBase + u * 64 + w * 8 + rsub) * Kb) + csrc * 16;

    floatx4 acc[MI][4];
#pragma unroll
    for (int m = 0; m < MI; m++)
#pragma unroll
        for (int n = 0; n < 4; n++) acc[m][n] = floatx4{0.f, 0.f, 0.f, 0.f};
    bf16x8 af[MI], bfr[4];

#define LDFRAGS(BUF, CK) do { \
    _Pragma("unroll") for (int mh_ = 0; mh_ < MH/2; mh_++) \
    _Pragma("unroll") for (int m_ = 0; m_ < 4; m_++) \
        af[mh_*4+m_] = *(const bf16x8*)(rdA + (BUF)*(MH*8192) + (mh_*64 + m_*16)*128 + (CK)); \
    _Pragma("unroll") for (int n_ = 0; n_ < 4; n_++) \
        bfr[n_] = *(const bf16x8*)(rdB + (BUF)*32768 + n_*2048 + (CK)); } while(0)

// swapped operands: D = B^T-frag x A-frag -> lane holds 4 consecutive N-cols per acc reg
#define DOMFMA() do { \
    _Pragma("unroll") for (int mi_ = 0; mi_ < MI; mi_++) \
    _Pragma("unroll") for (int n_ = 0; n_ < 4; n_++) \
        acc[mi_][n_] = __builtin_amdgcn_mfma_f32_16x16x32_bf16(bfr[n_], af[mi_], acc[mi_][n_], 0,0,0); } while(0)

#define STAGE(BUF, OFF) do { \
    _Pragma("unroll") for (int u_ = 0; u_ < MH; u_++) \
        gload16(pA[u_] + (OFF), ldsw + (BUF)*(MH*8192) + u_*8192); \
    _Pragma("unroll") for (int u_ = 0; u_ < 4; u_++) \
        gload16(pB[u_] + (OFF), ldsw + MH*16384 + (BUF)*32768 + u_*8192); } while(0)

#define VMN do { if constexpr (MH == 4) { asm volatile("s_waitcnt vmcnt(8)"); } \
                 else { asm volatile("s_waitcnt vmcnt(6)"); } } while(0)

    const int nkt = K >> 6;   // K-tiles (32 or 64)

    // prologue: tiles 0 and 1; drain tile 0, keep tile 1 in flight
    STAGE(0, 0);
    STAGE(1, 128);
    VMN; BARR;

    for (int t = 0; t < nkt; t++) {
        const int buf = t & 1;
        const size_t off2 = (size_t)((t + 2 < nkt) ? (t + 2) : (nkt - 1)) * 128;
        LDFRAGS(buf, cb0);
        LGKM0;
        PRIO1; DOMFMA(); PRIO0;
        LDFRAGS(buf, cb1);
        LGKM0;
        BARR;                 // all waves done reading buf
        STAGE(buf, off2);     // tile t+2 into freed buf
        VMN;                  // tile t+1 fully landed (t+2 stays in flight)
        BARR;                 // publish
        PRIO1; DOMFMA(); PRIO0;   // register-only; overlaps t+2 staging
    }
#undef LDFRAGS
#undef DOMFMA
#undef STAGE
#undef VMN

    // ---------------- epilogue (C^T layout: lane&15 = M-row, (lane>>4)*4+reg = N-col) ----------------
    const int cg = (lane >> 4) * 4;
    if constexpr (EPI == 0) {
#pragma unroll
        for (int mi = 0; mi < MI; mi++)
#pragma unroll
            for (int n = 0; n < 4; n++) {
                long row = rowBase + wm * WBAND + mi * 16 + lrow;
                long col = colBase + wn * 64 + n * 16 + cg;
                ushort4v o = {f2bf(acc[mi][n][0]), f2bf(acc[mi][n][1]),
                              f2bf(acc[mi][n][2]), f2bf(acc[mi][n][3])};
                *(ushort4v*)&Cbf[row * ldc + col] = o;
            }
    } else if constexpr (EPI == 2) {
        if (colBase >= DINNER) {
            // W_xp region -> bc[NTOK][256], float4 stores
#pragma unroll
            for (int mi = 0; mi < MI; mi++)
#pragma unroll
                for (int n = 0; n < 4; n++) {
                    long row = rowBase + wm * WBAND + mi * 16 + lrow;
                    long col = colBase - DINNER + wn * 64 + n * 16 + cg;
                    *(floatx4*)&bcout[row * (2 * DSTATE) + col] = acc[mi][n];
                }
        } else {
            // delta region: softplus(acc + b_dt) summed over cols -> dmean atomics
            float4 bi[4];
#pragma unroll
            for (int n = 0; n < 4; n++)
                bi[n] = *(const float4*)&bias[colBase + wn * 64 + n * 16 + cg];
#pragma unroll
            for (int mi = 0; mi < MI; mi++) {
                float s = 0.f;
#pragma unroll
                for (int n = 0; n < 4; n++) {
                    s += softplusf(acc[mi][n][0] + bi[n].x);
                    s += softplusf(acc[mi][n][1] + bi[n].y);
                    s += softplusf(acc[mi][n][2] + bi[n].z);
                    s += softplusf(acc[mi][n][3] + bi[n].w);
                }
                s += __shfl_xor(s, 16);
                s += __shfl_xor(s, 32);
                if ((lane >> 4) == 0)
                    atomicAdd(&dmean[rowBase + wm * WBAND + mi * 16 + lrow], s);
            }
        }
    } else {  // EPI == 3: fp32 out + residual, float4
#pragma unroll
        for (int mi = 0; mi < MI; mi++)
#pragma unroll
            for (int n = 0; n < 4; n++) {
                long row = rowBase + wm * WBAND + mi * 16 + lrow;
                long col = colBase + wn * 64 + n * 16 + cg;
                floatx4 rv = *(const floatx4*)&resid[row * ldc + col];
                *(floatx4*)&Cf[row * ldc + col] = acc[mi][n] + rv;
            }
    }
}

// ---------------- causal depthwise conv1d + bias + silu ----------------
__global__ __launch_bounds__(256) void conv_silu_kernel(const unsigned short* __restrict__ xr,
                                                        const float* __restrict__ w,
                                                        const float* __restrict__ cb,
                                                        unsigned short* __restrict__ xc) {
    int idx = blockIdx.x * blockDim.x + threadIdx.x;   // NTOK * 512
    int d0 = (idx & 511) * 8;
    int bt = idx >> 9;
    int t = bt & (TT - 1);
    float acc[8];
#pragma unroll
    for (int j = 0; j < 8; j++) acc[j] = cb[d0 + j];
#pragma unroll
    for (int k = 0; k < DCONV; k++) {
        int ts = t - (DCONV - 1) + k;
        if (ts < 0) continue;
        ushort8v v = *(const ushort8v*)&xr[(long)(bt - (DCONV - 1) + k) * (2 * DINNER) + d0];
#pragma unroll
        for (int j = 0; j < 8; j++) acc[j] += bf2f(v[j]) * w[(d0 + j) * DCONV + k];
    }
    ushort8v ov;
#pragma unroll
    for (int j = 0; j < 8; j++) ov[j] = f2bf(siluf(acc[j]));
    *(ushort8v*)&xc[(long)bt * DINNER + d0] = ov;
}

// ---------------- sequential selective-scan (1 wave per batch) ----------------
__global__ void scan_kernel(const float* __restrict__ dmean, const float* __restrict__ bcmat,
                            const float* __restrict__ A_log, float* __restrict__ ys) {
    int b = blockIdx.x, lane = threadIdx.x;   // 64 lanes, 2 states each
    float A0 = -expf(A_log[lane]);
    float A1 = -expf(A_log[lane + 64]);
    float h0 = 0.f, h1 = 0.f;
    const float inv = 1.f / (float)DINNER;
    const float* rowp = bcmat + (long)b * TT * (2 * DSTATE);
    const float* dmp = dmean + b * TT;
    float B0 = rowp[lane], B1 = rowp[64 + lane];
    float C0 = rowp[128 + lane], C1 = rowp[192 + lane];
    float DM = dmp[0];
    for (int t = 0; t < TT; t++) {
        float nB0 = 0.f, nB1 = 0.f, nC0 = 0.f, nC1 = 0.f, nDM = 0.f;
        if (t + 1 < TT) {
            const float* nx = rowp + (long)(t + 1) * 256;
            nB0 = nx[lane]; nB1 = nx[64 + lane];
            nC0 = nx[128 + lane]; nC1 = nx[192 + lane];
            nDM = dmp[t + 1];
        }
        float dm = DM * inv;
        h0 = h0 * __expf(dm * A0) + B0;
        h1 = h1 * __expf(dm * A1) + B1;
        float v = h0 * C0 + h1 * C1;
#pragma unroll
        for (int off = 32; off >= 1; off >>= 1) v += __shfl_xor(v, off);
        if (lane == 0) ys[b * TT + t] = v;
        B0 = nB0; B1 = nB1; C0 = nC0; C1 = nC1; DM = nDM;
    }
}

// ---------------- y = (ys + D_skip*xc) * silu(res) ----------------
__global__ __launch_bounds__(256) void ycomb_kernel(const float* __restrict__ ys,
                                                    const unsigned short* __restrict__ xc,
                                                    const unsigned short* __restrict__ xr,
                                                    const float* __restrict__ dskip,
                                                    unsigned short* __restrict__ yc) {
    int idx = blockIdx.x * blockDim.x + threadIdx.x;
    int d0 = (idx & 511) * 8;
    int bt = idx >> 9;
    float y = ys[bt];
    ushort8v xcv = *(const ushort8v*)&xc[(long)bt * DINNER + d0];
    ushort8v rv = *(const ushort8v*)&xr[(long)bt * (2 * DINNER) + DINNER + d0];
    ushort8v ov;
#pragma unroll
    for (int j = 0; j < 8; j++) {
        float val = (y + dskip[d0 + j] * bf2f(xcv[j])) * siluf(bf2f(rv[j]));
        ov[j] = f2bf(val);
    }
    *(ushort8v*)&yc[(long)bt * DINNER + d0] = ov;
}

extern "C" void kernel_launch(void* const* d_in, const int* in_sizes, int n_in,
                              void* d_out, int out_size, void* d_ws, size_t ws_size,
                              hipStream_t stream) {
    const float* x      = (const float*)d_in[0];
    const float* ln_g   = (const float*)d_in[1];
    const float* ln_b   = (const float*)d_in[2];
    const float* W_in   = (const float*)d_in[3];
    const float* conv_w = (const float*)d_in[4];
    const float* conv_b = (const float*)d_in[5];
    const float* W_xp   = (const float*)d_in[6];
    const float* W_dt   = (const float*)d_in[7];
    const float* b_dt   = (const float*)d_in[8];
    const float* A_log  = (const float*)d_in[9];
    const float* D_skip = (const float*)d_in[10];
    const float* W_out  = (const float*)d_in[11];
    float* out = (float*)d_out;

    // workspace carve
    char* ws = (char*)d_ws;
    const size_t nWin  = (size_t)2 * DINNER * DMODEL;
    const size_t nWdt  = (size_t)DINNER * DINNER;
    const size_t nWxp  = (size_t)2 * DSTATE * DINNER;
    const size_t nWout = (size_t)DMODEL * DINNER;

    unsigned short* wb_in  = (unsigned short*)ws; ws += nWin * 2;
    unsigned short* wb_cat = (unsigned short*)ws; ws += (nWdt + nWxp) * 2;
    unsigned short* wb_out = (unsigned short*)ws; ws += nWout * 2;
    unsigned short* xn = (unsigned short*)ws; ws += (size_t)NTOK * DMODEL * 2;
    unsigned short* xr = (unsigned short*)ws; ws += (size_t)NTOK * 2 * DINNER * 2;
    unsigned short* xc = (unsigned short*)ws; ws += (size_t)NTOK * DINNER * 2;
    unsigned short* yc = (unsigned short*)ws; ws += (size_t)NTOK * DINNER * 2;
    float* bc    = (float*)ws; ws += (size_t)NTOK * 2 * DSTATE * 4;
    float* dmean = (float*)ws; ws += (size_t)NTOK * 4;
    float* ysb   = (float*)ws; ws += (size_t)NTOK * 4;
    float* h0    = (float*)ws; ws += (size_t)NTOK * DMODEL * 4;
    float* h1    = (float*)ws; ws += (size_t)NTOK * DMODEL * 4;

    const float* hin = x;
    for (int l = 0; l < NLAYERS; l++) {
        float* hout = (l == NLAYERS - 1) ? out : ((l & 1) ? h1 : h0);

        cvt_kernel<<<(int)(nWin / 1024), 256, 0, stream>>>(W_in + (size_t)l * nWin, wb_in, (int)nWin);
        cvt_kernel<<<(int)(nWdt / 1024), 256, 0, stream>>>(W_dt + (size_t)l * nWdt, wb_cat, (int)nWdt);
        cvt_kernel<<<(int)(nWxp / 1024), 256, 0, stream>>>(W_xp + (size_t)l * nWxp, wb_cat + nWdt, (int)nWxp);
        cvt_kernel<<<(int)(nWout / 1024), 256, 0, stream>>>(W_out + (size_t)l * nWout, wb_out, (int)nWout);

        hipMemsetAsync(dmean, 0, (size_t)NTOK * 4, stream);

        // 1) LayerNorm
        ln_kernel<<<NTOK, 256, 0, stream>>>(hin, ln_g + l * DMODEL, ln_b + l * DMODEL, xn);

        // 2) x_and_res = xn @ W_in^T   [4096 x 8192], K=2048, BM=256: grid 16x32=512
        gemm256<0, 4><<<512, 512, 0, stream>>>(
            xn, wb_in, DMODEL, 32, 2 * DINNER, xr, nullptr, nullptr, nullptr, nullptr, nullptr);

        // 3) causal depthwise conv + silu
        conv_silu_kernel<<<NTOK * 512 / 256, 256, 0, stream>>>(
            xr, conv_w + (size_t)l * DINNER * DCONV, conv_b + (size_t)l * DINNER, xc);

        // 4) fused [W_dt; W_xp] GEMM: [4096 x 4352], K=4096, BM=128: grid 32x17=544
        gemm256<2, 2><<<544, 512, 0, stream>>>(
            xc, wb_cat, DINNER, 17, 0, nullptr, nullptr, nullptr,
            b_dt + (size_t)l * DINNER, dmean, bc);

        // 5) sequential scan -> ys
        scan_kernel<<<BB, 64, 0, stream>>>(dmean, bc, A_log + (size_t)l * DSTATE, ysb);

        // 6) y = (ys + D_skip*xc) * silu(res)
        ycomb_kernel<<<NTOK * 512 / 256, 256, 0, stream>>>(
            ysb, xc, xr, D_skip + (size_t)l * DINNER, yc);

        // 7) out = yc @ W_out^T + hin   [4096 x 2048], K=4096, BM=128: grid 32x8=256
        gemm256<3, 2><<<256, 512, 0, stream>>>(
            yc, wb_out, DINNER, 8, DMODEL, nullptr, hout, hin, nullptr, nullptr, nullptr);

        hin = hout;
    }
    (void)in_sizes; (void)n_in; (void)out_size; (void)ws_size;
}